// Round 13
// baseline (205.170 us; speedup 1.0000x reference)
//
#include <hip/hip_runtime.h>
#include <stdint.h>

typedef float f32x4 __attribute__((ext_vector_type(4)));
typedef __bf16 bf16x8 __attribute__((ext_vector_type(8)));

#define AS1 __attribute__((address_space(1)))
#define AS3 __attribute__((address_space(3)))

__device__ __forceinline__ unsigned short f2bf(float f) {
  uint32_t u = __builtin_bit_cast(uint32_t, f);
  return (unsigned short)((u + 0x7fffu + ((u >> 16) & 1u)) >> 16);
}
__device__ __forceinline__ float bf2f(unsigned short s) {
  uint32_t u = ((uint32_t)s) << 16;
  return __builtin_bit_cast(float, u);
}

// ---- merged prep: blocks 0..4095 pack x,h -> xh bf16 [8192][2048];
// blocks 4096..10239 transpose-pack six 1024x1024 f32 W into Bt1/Bt2 (N x K bf16).
__global__ __launch_bounds__(256) void prep_all(
    const float* __restrict__ x, const float* __restrict__ h,
    const float* __restrict__ W0, const float* __restrict__ W1,
    const float* __restrict__ W2, const float* __restrict__ W3,
    const float* __restrict__ W4, const float* __restrict__ W5,
    unsigned short* __restrict__ xh,
    unsigned short* __restrict__ Bt1, unsigned short* __restrict__ Bt2) {
  const int b = blockIdx.x;
  if (b < 4096) {
    const int n4 = (8192 * 1024) / 4;
    const float4* x4 = (const float4*)x;
    const float4* h4 = (const float4*)h;
    for (int idx = b * 256 + threadIdx.x; idx < n4; idx += 4096 * 256) {
      float4 vx = x4[idx];
      float4 vh = h4[idx];
      int row = idx >> 8;
      int c = (idx & 255) << 2;
      ushort4 px = { f2bf(vx.x), f2bf(vx.y), f2bf(vx.z), f2bf(vx.w) };
      ushort4 ph = { f2bf(vh.x), f2bf(vh.y), f2bf(vh.z), f2bf(vh.w) };
      *(ushort4*)(xh + (size_t)row * 2048 + c) = px;
      *(ushort4*)(xh + (size_t)row * 2048 + 1024 + c) = ph;
    }
    return;
  }
  __shared__ float t[32][33];
  const int z = (b - 4096) >> 10;
  const int ti = (b - 4096) & 1023;
  const float* W; unsigned short* dst; int rowOff, colOff;
  switch (z) {
    case 0: W = W0; dst = Bt1; rowOff = 0;    colOff = 0;    break;
    case 1: W = W1; dst = Bt1; rowOff = 0;    colOff = 1024; break;
    case 2: W = W2; dst = Bt1; rowOff = 1024; colOff = 0;    break;
    case 3: W = W3; dst = Bt1; rowOff = 1024; colOff = 1024; break;
    case 4: W = W4; dst = Bt2; rowOff = 0;    colOff = 0;    break;
    default: W = W5; dst = Bt2; rowOff = 0;   colOff = 1024; break;
  }
  const int n0 = (ti & 31) * 32, k0 = (ti >> 5) * 32;
  const int tx = threadIdx.x & 31, ty = threadIdx.x >> 5;
  for (int i = ty; i < 32; i += 8)
    t[i][tx] = W[(size_t)(k0 + i) * 1024 + n0 + tx];
  __syncthreads();
  for (int i = ty; i < 32; i += 8) {
    int n = n0 + i, k = k0 + tx;
    dst[(size_t)(rowOff + n) * 2048 + colOff + k] = f2bf(t[tx][i]);
  }
}

// ---- B-in-registers GEMM: A in LDS (dbuf, gload_lds, T2 swizzle), B loaded
// per-wave to REGISTERS one K-tile ahead (no barrier coupling, L2-resident).
// One barrier + one counted vmcnt per K-tile. BM=256, BK=64, 8 waves (2Mx4N),
// T1 XCD chunk swizzle, T5 setprio, slab-aligned wave ownership.
// Grid: 1D, 256 blocks.
template <int EPI, int BN>
__global__ __launch_bounds__(512, 1) void gru_gemm_breg(
    const unsigned short* __restrict__ xh,
    const unsigned short* __restrict__ hrA,
    const unsigned short* __restrict__ Bt,
    const float* __restrict__ bias0,
    const float* __restrict__ bias1,
    const unsigned short* __restrict__ u_in,
    unsigned short* __restrict__ u_out,
    unsigned short* __restrict__ hr_out,
    float* __restrict__ out) {
  constexpr int WN = BN / 64;       // 4 (G1) / 2 (G2)
  constexpr int NH = WN / 2;
  constexpr int ABUF = 32768;       // A buf: 256 rows x 128 B
  constexpr int NKT = 32;
  constexpr int VC = 2 * WN;        // outstanding B(t+1) loads at tile-end vmcnt
  __shared__ __align__(128) char smem[2 * ABUF];  // 64 KB (A only)

  const int tid = threadIdx.x;
  const int l = tid & 63;
  const int wid = tid >> 6;
  const int wr = wid >> 2, wc = wid & 3;

  // T1: XCD chunk swizzle (256 blocks = 8 chunks of 32)
  const int d = blockIdx.x;
  const int s = ((d & 7) << 5) + (d >> 3);
  const int tx = s & 7, ty = s >> 3;
  const int row0 = ty * 256;
  const int col0 = tx * BN;

  // A staging (inverse-swizzled global source; linear LDS dest)
  const int srow = tid >> 3;
  const int s0 = (tid & 7) ^ (srow & 7);
  const char* pAx = (const char*)xh + (size_t)(row0 + srow) * 4096 + s0 * 16;
  const char* pAh = (EPI == 1)
      ? (const char*)hrA + (size_t)(row0 + srow) * 2048 + s0 * 16
      : (const char*)xh;

  auto stage_A = [&](int t, int p) {
    if (t >= NKT) return;
    const size_t dd = (size_t)p * ABUF + (size_t)tid * 16;
    if (EPI == 1 && t >= 16) {
      const char* sp = pAh + (size_t)(t - 16) * 128;
#pragma unroll
      for (int jj = 0; jj < 4; ++jj)
        __builtin_amdgcn_global_load_lds((const AS1 void*)(sp + (size_t)jj * (64 * 2048)),
                                         (AS3 void*)(smem + dd + (size_t)jj * 8192), 16, 0, 0);
    } else {
      const char* sp = pAx + (size_t)t * 128;
#pragma unroll
      for (int jj = 0; jj < 4; ++jj)
        __builtin_amdgcn_global_load_lds((const AS1 void*)(sp + (size_t)jj * (64 * 4096)),
                                         (AS3 void*)(smem + dd + (size_t)jj * 8192), 16, 0, 0);
    }
  };

  // A ds_read addressing (T2 swizzle, slab-aligned)
  const int lm = l & 15, hi4 = l >> 4;
  const int xorv = (l & 7) << 4;
  const int cb0 = (hi4 * 16) ^ xorv;
  const int cb1 = (64 + hi4 * 16) ^ xorv;
  const int aslab = (wr * 64 + lm) * 128;

  // B global-register addressing: row = col0 + wc*16*NH + BROW(n) + lm
#define AROW(M) (((M) < 4) ? (M) * 16 : 128 + ((M) - 4) * 16)
#define BROW(N) (((N) < NH) ? (N) * 16 : BN / 2 + ((N) - NH) * 16)
  const char* pBr = (const char*)Bt + (size_t)(col0 + wc * 16 * NH + lm) * 4096 + hi4 * 16;

#define RD_A(P, M, KS) (*(const bf16x8*)(smem + (size_t)(P) * ABUF + aslab + AROW(M) * 128 + ((KS) ? cb1 : cb0)))
#define LD_B(DST, T) do { _Pragma("unroll") for (int n = 0; n < WN; ++n) { \
    DST[n][0] = *(const bf16x8*)(pBr + (size_t)BROW(n) * 4096 + (size_t)(T) * 128); \
    DST[n][1] = *(const bf16x8*)(pBr + (size_t)BROW(n) * 4096 + (size_t)(T) * 128 + 64); } } while (0)
#define MFMA_(D, AV, BV) D = __builtin_amdgcn_mfma_f32_16x16x32_bf16(AV, BV, D, 0, 0, 0)
#define TILE(P, B) do { \
    __builtin_amdgcn_s_setprio(1); \
    _Pragma("unroll") for (int m = 0; m < 8; ++m) { \
      bf16x8 av0 = RD_A(P, m, 0), av1 = RD_A(P, m, 1); \
      _Pragma("unroll") for (int n = 0; n < WN; ++n) { \
        MFMA_(acc[m][n], av0, B[n][0]); MFMA_(acc[m][n], av1, B[n][1]); } } \
    __builtin_amdgcn_s_setprio(0); } while (0)
#define BARF() do { __builtin_amdgcn_s_barrier(); asm volatile("" ::: "memory"); } while (0)

  f32x4 acc[8][WN] = {};
  bf16x8 bE[WN][2], bO[WN][2];

  // ---- prologue: stage A(0)->buf0; load B(0)->bE; confirm A(0) (B stays in flight)
  stage_A(0, 0);
  LD_B(bE, 0);
  asm volatile("s_waitcnt vmcnt(%0)" ::"i"(VC) : "memory");
  BARF();

  for (int i = 0; i < NKT / 2; ++i) {
    const bool lastp = (i == NKT / 2 - 1);
    // tile e = 2i: stage A(e+1)->buf1; load B(e+1)->bO; compute(buf0, bE)
    stage_A(2 * i + 1, 1);
    LD_B(bO, 2 * i + 1);
    TILE(0, bE);
    asm volatile("s_waitcnt vmcnt(%0)" ::"i"(VC) : "memory");  // A(e+1) confirmed
    BARF();
    // tile o = 2i+1: stage A(o+1)->buf0; load B(o+1)->bE; compute(buf1, bO)
    if (!lastp) {
      stage_A(2 * i + 2, 0);
      LD_B(bE, 2 * i + 2);
    }
    TILE(1, bO);
    if (!lastp) {
      asm volatile("s_waitcnt vmcnt(%0)" ::"i"(VC) : "memory");  // A(o+1) confirmed
      BARF();
    }
  }

  // ---- epilogue: C/D layout col=lane&15, row=(lane>>4)*4+j; slab ownership
#pragma unroll
  for (int m = 0; m < 8; ++m) {
#pragma unroll
    for (int n = 0; n < WN; ++n) {
      const int col = col0 + wc * 16 * NH + BROW(n) + lm;
      const int rowb = row0 + wr * 64 + AROW(m) + hi4 * 4;
#pragma unroll
      for (int j = 0; j < 4; ++j) {
        const int row = rowb + j;
        float v = acc[m][n][j];
        if (EPI == 0) {
          if (col < 1024) {
            float uv = 1.f / (1.f + __expf(-(v + bias0[col])));
            u_out[(size_t)row * 1024 + col] = f2bf(uv);
          } else {
            int c2 = col - 1024;
            float rv = 1.f / (1.f + __expf(-(v + bias1[c2])));
            float hv = bf2f(xh[(size_t)row * 2048 + 1024 + c2]);
            hr_out[(size_t)row * 1024 + c2] = f2bf(hv * rv);
          }
        } else {
          float e2x = __expf(2.f * (v + bias0[col]));
          float cp = (e2x - 1.f) / (e2x + 1.f);
          float uv = bf2f(u_in[(size_t)row * 1024 + col]);
          float hv = bf2f(xh[(size_t)row * 2048 + 1024 + col]);
          out[(size_t)row * 1024 + col] = uv * cp + (1.f - uv) * hv;
        }
      }
    }
  }
#undef AROW
#undef BROW
#undef RD_A
#undef LD_B
#undef MFMA_
#undef TILE
#undef BARF
}

extern "C" void kernel_launch(void* const* d_in, const int* in_sizes, int n_in,
                              void* d_out, int out_size, void* d_ws, size_t ws_size,
                              hipStream_t stream) {
  const float* x   = (const float*)d_in[0];
  const float* h   = (const float*)d_in[1];
  const float* Wxu = (const float*)d_in[2];
  const float* Whu = (const float*)d_in[3];
  const float* bu  = (const float*)d_in[4];
  const float* Wxr = (const float*)d_in[5];
  const float* Whr = (const float*)d_in[6];
  const float* br  = (const float*)d_in[7];
  const float* Wxc = (const float*)d_in[8];
  const float* Whc = (const float*)d_in[9];
  const float* bc  = (const float*)d_in[10];
  float* out = (float*)d_out;

  char* ws = (char*)d_ws;
  unsigned short* xh  = (unsigned short*)(ws);              // 33,554,432 B
  unsigned short* Bt1 = (unsigned short*)(ws + 33554432);   //  8,388,608 B
  unsigned short* Bt2 = (unsigned short*)(ws + 41943040);   //  4,194,304 B
  unsigned short* ubf = (unsigned short*)(ws + 46137344);   // 16,777,216 B
  unsigned short* hrb = (unsigned short*)(ws + 62914560);   // 16,777,216 B

  prep_all<<<10240, 256, 0, stream>>>(x, h, Wxu, Whu, Wxr, Whr, Wxc, Whc,
                                      xh, Bt1, Bt2);

  // GEMM1: [x|h](8192x2048) @ Bt1 -> u (bf16), hr=h*r (bf16)
  gru_gemm_breg<0, 256><<<256, 512, 0, stream>>>(xh, nullptr, Bt1, bu, br,
                                                 nullptr, ubf, hrb, nullptr);
  // GEMM2: [x|hr](8192x2048) @ Bt2 -> out f32
  gru_gemm_breg<1, 128><<<256, 512, 0, stream>>>(xh, hrb, Bt2, bc, nullptr,
                                                 ubf, nullptr, nullptr, out);
}